// Round 1
// baseline (1902.270 us; speedup 1.0000x reference)
//
#include <hip/hip_runtime.h>

#define N_NODES 100000
#define E_EDGES 600000
#define HID 128

// ---------------- last-edge-index per node (last-write-wins) ----------------
__global__ void k_last(const int* __restrict__ ei, int* __restrict__ last_src,
                       int* __restrict__ last_dst, int E) {
  int e = blockIdx.x * blockDim.x + threadIdx.x;
  if (e >= E) return;
  atomicMax(&last_src[ei[e]], e);
  atomicMax(&last_dst[ei[E + e]], e);
}

// ---------------- piecewise-linear edge-encoder table ----------------
// ee(a)_j = A[i][j]*a + B[i][j], i = #{breakpoints t < a}
__global__ void k_table(const float* __restrict__ W1g, const float* __restrict__ b1g,
                        const float* __restrict__ W2g, const float* __restrict__ b2g,
                        float* __restrict__ tabA, float* __restrict__ tabB,
                        float* __restrict__ tsort) {
  __shared__ float w1[128], b1[128], key[128];
  __shared__ int idx[128];
  __shared__ float w2[128][128];
  const int t = threadIdx.x;  // 128 threads
  w1[t] = W1g[t];
  b1[t] = b1g[t];
  for (int k = 0; k < 128; ++k) w2[k][t] = W2g[k * 128 + t];
  __syncthreads();
  float s0 = w1[t];
  key[t] = (s0 != 0.0f) ? (-b1[t] / s0) : __builtin_inff();
  idx[t] = t;
  // bitonic sort (key asc, payload idx)
  for (int size = 2; size <= 128; size <<= 1) {
    for (int stride = size >> 1; stride > 0; stride >>= 1) {
      __syncthreads();
      int p = t ^ stride;
      if (p > t) {
        bool up = ((t & size) == 0);
        float k1 = key[t], k2 = key[p];
        if (up == (k1 > k2)) {
          int i1 = idx[t], i2 = idx[p];
          key[t] = k2; key[p] = k1; idx[t] = i2; idx[p] = i1;
        }
      }
    }
  }
  __syncthreads();
  tsort[t] = key[t];
  // interval 0 (a -> -inf): active = {W1<0} u {W1==0 && b1>0}
  float A = 0.0f, B = b2g[t];
  for (int k = 0; k < 128; ++k) {
    float s = w1[k], bb = b1[k], w = w2[k][t];
    if (s < 0.0f) { A = fmaf(s, w, A); B = fmaf(bb, w, B); }
    else if (s == 0.0f && bb > 0.0f) { B = fmaf(bb, w, B); }
  }
  tabA[t] = A;
  tabB[t] = B;
  // sweep breakpoints: W1>0 activates, W1<0 deactivates
  for (int i = 0; i < 128; ++i) {
    float kv = key[i];
    int kk = idx[i];
    if (kv < __builtin_inff()) {
      float s = w1[kk], bb = b1[kk], w = w2[kk][t];
      if (s > 0.0f) { A = fmaf(s, w, A); B = fmaf(bb, w, B); }
      else { A = fmaf(-s, w, A); B = fmaf(-bb, w, B); }
    }
    tabA[(i + 1) * 128 + t] = A;
    tabB[(i + 1) * 128 + t] = B;
  }
}

// ---------------- msg = relu(h[src] + ee(a)), agg[dst] += msg ----------------
__global__ __launch_bounds__(256) void k_msg(
    const float* __restrict__ h, const int* __restrict__ ei,
    const float* __restrict__ ea, const float* __restrict__ tabA,
    const float* __restrict__ tabB, const float* __restrict__ tsort,
    float* __restrict__ agg, int E) {
  int e = (int)((blockIdx.x * 256 + threadIdx.x) >> 6);  // one edge per wave
  if (e >= E) return;
  int lane = threadIdx.x & 63;
  int s = ei[e], d = ei[E + e];
  float a = ea[e];
  int pos = 0;
#pragma unroll
  for (int st = 64; st > 0; st >>= 1)
    if (pos + st <= 128 && tsort[pos + st - 1] < a) pos += st;
  int j = lane * 2;
  float2 hv = *(const float2*)(h + (size_t)s * HID + j);
  float2 Av = *(const float2*)(tabA + (size_t)pos * HID + j);
  float2 Bv = *(const float2*)(tabB + (size_t)pos * HID + j);
  float m0 = fmaxf(hv.x + fmaf(Av.x, a, Bv.x), 0.0f);
  float m1 = fmaxf(hv.y + fmaf(Av.y, a, Bv.y), 0.0f);
  float* ap = agg + (size_t)d * HID + j;
  atomicAdd(ap, m0);
  atomicAdd(ap + 1, m1);
}

// ---------------- generic skinny GEMM: out = pre(in) @ W + bias ----------------
// MODE 0: in=x, epilogue = agg_edge(last_dst/last_src, enc)  -> h
// MODE 1: in=(1+eps)*h+agg, epilogue = store z2 + BN partial sums
// MODE 2: in=relu(z2*scale+shift), epilogue = (+relu) store h/out
template <int K, int M, int MODE, bool RELU_OUT>
__global__ __launch_bounds__(256) void k_gemm(
    const float* __restrict__ in0, const float* __restrict__ in1,
    const float* __restrict__ W, const float* __restrict__ bias,
    float* __restrict__ out, const float* __restrict__ pre_a,
    const float* __restrict__ pre_b, const float* __restrict__ epsP,
    float* __restrict__ colsum, float* __restrict__ colsumsq,
    const int* __restrict__ last_dst, const int* __restrict__ last_src,
    const float* __restrict__ ea, const float* __restrict__ encW,
    const float* __restrict__ encb) {
  constexpr int BM = 32;
  constexpr int NT = 256;
  constexpr int CG = NT / M;   // row groups
  constexpr int RT = BM / CG;  // rows per thread
  constexpr int LDK = K + 4;   // pad keeps float4 alignment, breaks bank stride
  __shared__ float hs[BM][LDK];
  const int t = threadIdx.x;
  const size_t row0 = (size_t)blockIdx.x * BM;
  float ep1 = 1.0f;
  if (MODE == 1) ep1 = 1.0f + *epsP;
#pragma unroll
  for (int i = 0; i < BM * K / (NT * 4); ++i) {
    int eidx = (i * NT + t) * 4;
    int r = eidx / K, c = eidx % K;
    float4 v = *(const float4*)(in0 + (row0 + r) * K + c);
    if (MODE == 1) {
      float4 av = *(const float4*)(in1 + (row0 + r) * K + c);
      v.x = fmaf(ep1, v.x, av.x); v.y = fmaf(ep1, v.y, av.y);
      v.z = fmaf(ep1, v.z, av.z); v.w = fmaf(ep1, v.w, av.w);
    }
    if (MODE == 2) {
      float4 sc = *(const float4*)(pre_a + c);
      float4 sh = *(const float4*)(pre_b + c);
      v.x = fmaxf(fmaf(v.x, sc.x, sh.x), 0.0f);
      v.y = fmaxf(fmaf(v.y, sc.y, sh.y), 0.0f);
      v.z = fmaxf(fmaf(v.z, sc.z, sh.z), 0.0f);
      v.w = fmaxf(fmaf(v.w, sc.w, sh.w), 0.0f);
    }
    *(float4*)&hs[r][c] = v;
  }
  __syncthreads();
  const int j = t % M;
  const int rbase = (t / M) * RT;
  float acc[RT];
#pragma unroll
  for (int r = 0; r < RT; ++r) acc[r] = 0.0f;
  const float* Wp = W + j;
  for (int k = 0; k < K; k += 4) {
    float w0 = Wp[(size_t)(k + 0) * M];
    float w1 = Wp[(size_t)(k + 1) * M];
    float w2 = Wp[(size_t)(k + 2) * M];
    float w3 = Wp[(size_t)(k + 3) * M];
#pragma unroll
    for (int r = 0; r < RT; ++r) {
      float4 h4 = *(const float4*)&hs[rbase + r][k];
      acc[r] = fmaf(h4.x, w0, acc[r]);
      acc[r] = fmaf(h4.y, w1, acc[r]);
      acc[r] = fmaf(h4.z, w2, acc[r]);
      acc[r] = fmaf(h4.w, w3, acc[r]);
    }
  }
  float b = bias[j];
  if (MODE == 1) {
    float s1 = 0.0f, s2 = 0.0f;
#pragma unroll
    for (int r = 0; r < RT; ++r) {
      float v = acc[r] + b;
      out[(row0 + rbase + r) * M + j] = v;
      s1 += v;
      s2 = fmaf(v, v, s2);
    }
    atomicAdd(&colsum[j], s1);
    atomicAdd(&colsumsq[j], s2);
  } else if (MODE == 2) {
#pragma unroll
    for (int r = 0; r < RT; ++r) {
      float v = acc[r] + b;
      if (RELU_OUT) v = fmaxf(v, 0.0f);
      out[(row0 + rbase + r) * M + j] = v;
    }
  } else {
    float ew = encW[j], eb = encb[j];
#pragma unroll
    for (int r = 0; r < RT; ++r) {
      size_t R = row0 + rbase + r;
      float v = acc[r] + b;
      int ld = last_dst[R];
      int ls = last_src[R];
      int e = (ld >= 0) ? ld : ls;  // dst assignment overwrites src assignment
      if (e >= 0) v = fmaxf(v + fmaf(ea[e], ew, eb), 0.0f);
      out[R * (size_t)M + j] = v;
    }
  }
}

// ---------------- BN finalize: scale/shift per column ----------------
__global__ void k_bnfin(const float* __restrict__ colsum, const float* __restrict__ colsumsq,
                        const float* __restrict__ g, const float* __restrict__ bb,
                        float* __restrict__ scale, float* __restrict__ shift) {
  int j = threadIdx.x;  // 256
  const float inv = 1.0f / (float)N_NODES;
  float mu = colsum[j] * inv;
  float var = colsumsq[j] * inv - mu * mu;
  float sc = g[j] * rsqrtf(var + 1e-5f);
  scale[j] = sc;
  shift[j] = fmaf(-mu, sc, bb[j]);
}

extern "C" void kernel_launch(void* const* d_in, const int* in_sizes, int n_in,
                              void* d_out, int out_size, void* d_ws, size_t ws_size,
                              hipStream_t stream) {
  const float* x     = (const float*)d_in[0];
  const int*   ei    = (const int*)d_in[1];
  const float* ea    = (const float*)d_in[2];
  const float* lin_W = (const float*)d_in[3];
  const float* lin_b = (const float*)d_in[4];
  const float* enc_W = (const float*)d_in[5];
  const float* enc_b = (const float*)d_in[6];
  const float* eps   = (const float*)d_in[7];
  const float* e1_W  = (const float*)d_in[8];
  const float* e1_b  = (const float*)d_in[9];
  const float* e2_W  = (const float*)d_in[10];
  const float* e2_b  = (const float*)d_in[11];
  const float* m1_W  = (const float*)d_in[12];
  const float* m1_b  = (const float*)d_in[13];
  const float* bn_g  = (const float*)d_in[14];
  const float* bn_b  = (const float*)d_in[15];
  const float* m2_W  = (const float*)d_in[16];
  const float* m2_b  = (const float*)d_in[17];
  float* hbuf = (float*)d_out;  // h lives in d_out; final GEMM2 overwrites it

  float* ws = (float*)d_ws;
  size_t o = 0;
  float* agg = ws;                 o += (size_t)N_NODES * 128;
  float* z2 = ws + o;              o += (size_t)N_NODES * 256;
  int* last_dst = (int*)(ws + o);  o += N_NODES;
  int* last_src = (int*)(ws + o);  o += N_NODES;
  float* tabA = ws + o;            o += 129 * 128;
  float* tabB = ws + o;            o += 129 * 128;
  float* tsort = ws + o;           o += 128;
  float* colsum = ws + o;          o += 256;
  float* colsumsq = ws + o;        o += 256;
  float* scale = ws + o;           o += 256;
  float* shift = ws + o;           o += 256;
  if (ws_size < o * sizeof(float)) return;

  hipMemsetAsync(last_dst, 0xFF, 2 * (size_t)N_NODES * sizeof(int), stream);
  k_last<<<(E_EDGES + 255) / 256, 256, 0, stream>>>(ei, last_src, last_dst, E_EDGES);

  // h = x @ lin_W + lin_b, then agg_edge epilogue
  k_gemm<128, 128, 0, false><<<N_NODES / 32, 256, 0, stream>>>(
      x, nullptr, lin_W, lin_b, hbuf, nullptr, nullptr, nullptr, nullptr, nullptr,
      last_dst, last_src, ea, enc_W, enc_b);

  for (int l = 0; l < 2; ++l) {
    k_table<<<1, 128, 0, stream>>>(e1_W + l * 128, e1_b + l * 128,
                                   e2_W + l * 128 * 128, e2_b + l * 128,
                                   tabA, tabB, tsort);
    hipMemsetAsync(agg, 0, (size_t)N_NODES * 128 * sizeof(float), stream);
    k_msg<<<E_EDGES / 4, 256, 0, stream>>>(hbuf, ei, ea, tabA, tabB, tsort, agg, E_EDGES);
    hipMemsetAsync(colsum, 0, 512 * sizeof(float), stream);
    k_gemm<128, 256, 1, false><<<N_NODES / 32, 256, 0, stream>>>(
        hbuf, agg, m1_W + l * 128 * 256, m1_b + l * 256, z2, nullptr, nullptr,
        eps + l, colsum, colsumsq, nullptr, nullptr, nullptr, nullptr, nullptr);
    k_bnfin<<<1, 256, 0, stream>>>(colsum, colsumsq, bn_g + l * 256, bn_b + l * 256,
                                   scale, shift);
    if (l == 0) {
      k_gemm<256, 128, 2, true><<<N_NODES / 32, 256, 0, stream>>>(
          z2, nullptr, m2_W + l * 256 * 128, m2_b + l * 128, hbuf, scale, shift,
          nullptr, nullptr, nullptr, nullptr, nullptr, nullptr, nullptr, nullptr);
    } else {
      k_gemm<256, 128, 2, false><<<N_NODES / 32, 256, 0, stream>>>(
          z2, nullptr, m2_W + l * 256 * 128, m2_b + l * 128, hbuf, scale, shift,
          nullptr, nullptr, nullptr, nullptr, nullptr, nullptr, nullptr, nullptr);
    }
  }
}

// Round 2
// 1386.240 us; speedup vs baseline: 1.3723x; 1.3723x over previous
//
#include <hip/hip_runtime.h>

#define N_NODES 100000
#define E_EDGES 600000
#define HID 128

// ------------- last-edge (last-write-wins) + dst-degree histogram -------------
__global__ void k_last(const int* __restrict__ ei, int* __restrict__ last_src,
                       int* __restrict__ last_dst, int* __restrict__ deg, int E) {
  int e = blockIdx.x * blockDim.x + threadIdx.x;
  if (e >= E) return;
  int s = ei[e], d = ei[E + e];
  atomicMax(&last_src[s], e);
  atomicMax(&last_dst[d], e);
  atomicAdd(&deg[d], 1);
}

// ------------- 2-level exclusive scan over deg (CSR row offsets) -------------
__global__ __launch_bounds__(256) void k_scan1(const int* __restrict__ deg,
                                               int* __restrict__ excl,
                                               int* __restrict__ bsum, int n) {
  __shared__ int sh[256];
  int b = blockIdx.x, t = threadIdx.x;
  int i0 = b * 1024 + t * 4;
  int v0 = (i0 + 0 < n) ? deg[i0 + 0] : 0;
  int v1 = (i0 + 1 < n) ? deg[i0 + 1] : 0;
  int v2 = (i0 + 2 < n) ? deg[i0 + 2] : 0;
  int v3 = (i0 + 3 < n) ? deg[i0 + 3] : 0;
  int tsum = v0 + v1 + v2 + v3;
  sh[t] = tsum;
  __syncthreads();
  for (int off = 1; off < 256; off <<= 1) {
    int add = (t >= off) ? sh[t - off] : 0;
    __syncthreads();
    sh[t] += add;
    __syncthreads();
  }
  int ex = sh[t] - tsum;
  if (i0 + 0 < n) excl[i0 + 0] = ex;
  if (i0 + 1 < n) excl[i0 + 1] = ex + v0;
  if (i0 + 2 < n) excl[i0 + 2] = ex + v0 + v1;
  if (i0 + 3 < n) excl[i0 + 3] = ex + v0 + v1 + v2;
  if (t == 255) bsum[b] = sh[255];
}

__global__ void k_scan2(const int* __restrict__ bsum, int* __restrict__ boff, int nb) {
  __shared__ int sh[128];
  int t = threadIdx.x;
  int v = (t < nb) ? bsum[t] : 0;
  sh[t] = v;
  __syncthreads();
  for (int off = 1; off < 128; off <<= 1) {
    int add = (t >= off) ? sh[t - off] : 0;
    __syncthreads();
    sh[t] += add;
    __syncthreads();
  }
  if (t < nb) boff[t] = sh[t] - v;
}

// ------------- scatter edges into dst buckets: (src, attr) pairs -------------
__global__ void k_scatter(const int* __restrict__ ei, const float* __restrict__ ea,
                          const int* __restrict__ excl, const int* __restrict__ boff,
                          int* __restrict__ cnt, int* __restrict__ swv,
                          float* __restrict__ awv, int E) {
  int e = blockIdx.x * blockDim.x + threadIdx.x;
  if (e >= E) return;
  int d = ei[E + e];
  int p = excl[d] + boff[d >> 10] + atomicAdd(&cnt[d], 1);
  swv[p] = ei[e];
  awv[p] = ea[e];
}

// ---------------- piecewise-linear edge-encoder table ----------------
__global__ void k_table(const float* __restrict__ W1g, const float* __restrict__ b1g,
                        const float* __restrict__ W2g, const float* __restrict__ b2g,
                        float* __restrict__ tabA, float* __restrict__ tabB,
                        float* __restrict__ tsort) {
  __shared__ float w1[128], b1[128], key[128];
  __shared__ int idx[128];
  __shared__ float w2[128][128];
  const int t = threadIdx.x;  // 128 threads
  w1[t] = W1g[t];
  b1[t] = b1g[t];
  for (int k = 0; k < 128; ++k) w2[k][t] = W2g[k * 128 + t];
  __syncthreads();
  float s0 = w1[t];
  key[t] = (s0 != 0.0f) ? (-b1[t] / s0) : __builtin_inff();
  idx[t] = t;
  for (int size = 2; size <= 128; size <<= 1) {
    for (int stride = size >> 1; stride > 0; stride >>= 1) {
      __syncthreads();
      int p = t ^ stride;
      if (p > t) {
        bool up = ((t & size) == 0);
        float k1 = key[t], k2 = key[p];
        if (up == (k1 > k2)) {
          int i1 = idx[t], i2 = idx[p];
          key[t] = k2; key[p] = k1; idx[t] = i2; idx[p] = i1;
        }
      }
    }
  }
  __syncthreads();
  tsort[t] = key[t];
  float A = 0.0f, B = b2g[t];
  for (int k = 0; k < 128; ++k) {
    float s = w1[k], bb = b1[k], w = w2[k][t];
    if (s < 0.0f) { A = fmaf(s, w, A); B = fmaf(bb, w, B); }
    else if (s == 0.0f && bb > 0.0f) { B = fmaf(bb, w, B); }
  }
  tabA[t] = A;
  tabB[t] = B;
  for (int i = 0; i < 128; ++i) {
    float kv = key[i];
    int kk = idx[i];
    if (kv < __builtin_inff()) {
      float s = w1[kk], bb = b1[kk], w = w2[kk][t];
      if (s > 0.0f) { A = fmaf(s, w, A); B = fmaf(bb, w, B); }
      else { A = fmaf(-s, w, A); B = fmaf(-bb, w, B); }
    }
    tabA[(i + 1) * 128 + t] = A;
    tabB[(i + 1) * 128 + t] = B;
  }
}

// ------- per-node gather-aggregate: zin[n] = (1+eps)*h[n] + sum relu(...) -------
__global__ __launch_bounds__(256) void k_agg(
    const float* __restrict__ h, const int* __restrict__ swv,
    const float* __restrict__ awv, const int* __restrict__ excl,
    const int* __restrict__ boff, const float* __restrict__ tabA,
    const float* __restrict__ tabB, const float* __restrict__ tsort,
    const float* __restrict__ epsP, float* __restrict__ zin, int N, int E) {
  int w = (int)((blockIdx.x * 256 + threadIdx.x) >> 6);  // one wave per node
  if (w >= N) return;
  int lane = threadIdx.x & 63;
  int start = excl[w] + boff[w >> 10];
  int end = (w + 1 < N) ? (excl[w + 1] + boff[(w + 1) >> 10]) : E;
  int j = lane * 2;
  float a0 = 0.0f, a1 = 0.0f;
  for (int i = start; i < end; ++i) {
    int s = swv[i];
    float a = awv[i];
    int pos = 0;
#pragma unroll
    for (int st = 64; st > 0; st >>= 1)
      if (pos + st <= 128 && tsort[pos + st - 1] < a) pos += st;
    float2 hv = *(const float2*)(h + (size_t)s * HID + j);
    float2 Av = *(const float2*)(tabA + (size_t)pos * HID + j);
    float2 Bv = *(const float2*)(tabB + (size_t)pos * HID + j);
    a0 += fmaxf(hv.x + fmaf(Av.x, a, Bv.x), 0.0f);
    a1 += fmaxf(hv.y + fmaf(Av.y, a, Bv.y), 0.0f);
  }
  float ep1 = 1.0f + *epsP;
  float2 hn = *(const float2*)(h + (size_t)w * HID + j);
  float2 o;
  o.x = fmaf(ep1, hn.x, a0);
  o.y = fmaf(ep1, hn.y, a1);
  *(float2*)(zin + (size_t)w * HID + j) = o;
}

// ---------------- generic skinny GEMM: out = pre(in) @ W + bias ----------------
// MODE 0: in=x, epilogue = agg_edge(last_dst/last_src, enc)  -> h
// MODE 1: in=zin, epilogue = store z2 + BN partial sums
// MODE 2: in=relu(z2*scale+shift), epilogue = (+relu) store h/out
template <int K, int M, int MODE, bool RELU_OUT>
__global__ __launch_bounds__(256) void k_gemm(
    const float* __restrict__ in0, const float* __restrict__ W,
    const float* __restrict__ bias, float* __restrict__ out,
    const float* __restrict__ pre_a, const float* __restrict__ pre_b,
    float* __restrict__ colsum, float* __restrict__ colsumsq,
    const int* __restrict__ last_dst, const int* __restrict__ last_src,
    const float* __restrict__ ea, const float* __restrict__ encW,
    const float* __restrict__ encb) {
  constexpr int BM = 32;
  constexpr int NT = 256;
  constexpr int CG = NT / M;   // row groups
  constexpr int RT = BM / CG;  // rows per thread
  constexpr int LDK = K + 4;
  __shared__ float hs[BM][LDK];
  const int t = threadIdx.x;
  const size_t row0 = (size_t)blockIdx.x * BM;
#pragma unroll
  for (int i = 0; i < BM * K / (NT * 4); ++i) {
    int eidx = (i * NT + t) * 4;
    int r = eidx / K, c = eidx % K;
    float4 v = *(const float4*)(in0 + (row0 + r) * K + c);
    if (MODE == 2) {
      float4 sc = *(const float4*)(pre_a + c);
      float4 sh = *(const float4*)(pre_b + c);
      v.x = fmaxf(fmaf(v.x, sc.x, sh.x), 0.0f);
      v.y = fmaxf(fmaf(v.y, sc.y, sh.y), 0.0f);
      v.z = fmaxf(fmaf(v.z, sc.z, sh.z), 0.0f);
      v.w = fmaxf(fmaf(v.w, sc.w, sh.w), 0.0f);
    }
    *(float4*)&hs[r][c] = v;
  }
  __syncthreads();
  const int j = t % M;
  const int rbase = (t / M) * RT;
  float acc[RT];
#pragma unroll
  for (int r = 0; r < RT; ++r) acc[r] = 0.0f;
  const float* Wp = W + j;
  for (int k = 0; k < K; k += 4) {
    float w0 = Wp[(size_t)(k + 0) * M];
    float w1 = Wp[(size_t)(k + 1) * M];
    float w2 = Wp[(size_t)(k + 2) * M];
    float w3 = Wp[(size_t)(k + 3) * M];
#pragma unroll
    for (int r = 0; r < RT; ++r) {
      float4 h4 = *(const float4*)&hs[rbase + r][k];
      acc[r] = fmaf(h4.x, w0, acc[r]);
      acc[r] = fmaf(h4.y, w1, acc[r]);
      acc[r] = fmaf(h4.z, w2, acc[r]);
      acc[r] = fmaf(h4.w, w3, acc[r]);
    }
  }
  float b = bias[j];
  if (MODE == 1) {
    float s1 = 0.0f, s2 = 0.0f;
#pragma unroll
    for (int r = 0; r < RT; ++r) {
      float v = acc[r] + b;
      out[(row0 + rbase + r) * M + j] = v;
      s1 += v;
      s2 = fmaf(v, v, s2);
    }
    atomicAdd(&colsum[j], s1);
    atomicAdd(&colsumsq[j], s2);
  } else if (MODE == 2) {
#pragma unroll
    for (int r = 0; r < RT; ++r) {
      float v = acc[r] + b;
      if (RELU_OUT) v = fmaxf(v, 0.0f);
      out[(row0 + rbase + r) * M + j] = v;
    }
  } else {
    float ew = encW[j], eb = encb[j];
#pragma unroll
    for (int r = 0; r < RT; ++r) {
      size_t R = row0 + rbase + r;
      float v = acc[r] + b;
      int ld = last_dst[R];
      int ls = last_src[R];
      int e = (ld >= 0) ? ld : ls;  // dst assignment overwrites src assignment
      if (e >= 0) v = fmaxf(v + fmaf(ea[e], ew, eb), 0.0f);
      out[R * (size_t)M + j] = v;
    }
  }
}

// ---------------- BN finalize: scale/shift per column ----------------
__global__ void k_bnfin(const float* __restrict__ colsum, const float* __restrict__ colsumsq,
                        const float* __restrict__ g, const float* __restrict__ bb,
                        float* __restrict__ scale, float* __restrict__ shift) {
  int j = threadIdx.x;  // 256
  const float inv = 1.0f / (float)N_NODES;
  float mu = colsum[j] * inv;
  float var = colsumsq[j] * inv - mu * mu;
  float sc = g[j] * rsqrtf(var + 1e-5f);
  scale[j] = sc;
  shift[j] = fmaf(-mu, sc, bb[j]);
}

extern "C" void kernel_launch(void* const* d_in, const int* in_sizes, int n_in,
                              void* d_out, int out_size, void* d_ws, size_t ws_size,
                              hipStream_t stream) {
  const float* x     = (const float*)d_in[0];
  const int*   ei    = (const int*)d_in[1];
  const float* ea    = (const float*)d_in[2];
  const float* lin_W = (const float*)d_in[3];
  const float* lin_b = (const float*)d_in[4];
  const float* enc_W = (const float*)d_in[5];
  const float* enc_b = (const float*)d_in[6];
  const float* eps   = (const float*)d_in[7];
  const float* e1_W  = (const float*)d_in[8];
  const float* e1_b  = (const float*)d_in[9];
  const float* e2_W  = (const float*)d_in[10];
  const float* e2_b  = (const float*)d_in[11];
  const float* m1_W  = (const float*)d_in[12];
  const float* m1_b  = (const float*)d_in[13];
  const float* bn_g  = (const float*)d_in[14];
  const float* bn_b  = (const float*)d_in[15];
  const float* m2_W  = (const float*)d_in[16];
  const float* m2_b  = (const float*)d_in[17];
  float* hbuf = (float*)d_out;  // h lives in d_out; final GEMM2 overwrites it

  float* ws = (float*)d_ws;
  size_t o = 0;
  float* zin = ws;                 o += (size_t)N_NODES * 128;
  float* z2 = ws + o;              o += (size_t)N_NODES * 256;
  int* last_dst = (int*)(ws + o);  o += N_NODES;
  int* last_src = (int*)(ws + o);  o += N_NODES;
  int* deg = (int*)(ws + o);       o += N_NODES;
  int* cnt = (int*)(ws + o);       o += N_NODES;
  int* excl = (int*)(ws + o);      o += N_NODES;
  int* bsum = (int*)(ws + o);      o += 128;
  int* boff = (int*)(ws + o);      o += 128;
  int* swv = (int*)(ws + o);       o += E_EDGES;
  float* awv = ws + o;             o += E_EDGES;
  float* tabA = ws + o;            o += 129 * 128;
  float* tabB = ws + o;            o += 129 * 128;
  float* tsort = ws + o;           o += 128;
  float* colsum = ws + o;          o += 256;
  float* colsumsq = ws + o;        o += 256;
  float* scale = ws + o;           o += 256;
  float* shift = ws + o;           o += 256;
  if (ws_size < o * sizeof(float)) return;

  const int NB_SCAN = (N_NODES + 1023) / 1024;  // 98

  hipMemsetAsync(last_dst, 0xFF, 2 * (size_t)N_NODES * sizeof(int), stream);
  hipMemsetAsync(deg, 0, 2 * (size_t)N_NODES * sizeof(int), stream);  // deg + cnt
  k_last<<<(E_EDGES + 255) / 256, 256, 0, stream>>>(ei, last_src, last_dst, deg, E_EDGES);
  k_scan1<<<NB_SCAN, 256, 0, stream>>>(deg, excl, bsum, N_NODES);
  k_scan2<<<1, 128, 0, stream>>>(bsum, boff, NB_SCAN);
  k_scatter<<<(E_EDGES + 255) / 256, 256, 0, stream>>>(ei, ea, excl, boff, cnt, swv, awv, E_EDGES);

  // h = x @ lin_W + lin_b, then agg_edge epilogue
  k_gemm<128, 128, 0, false><<<N_NODES / 32, 256, 0, stream>>>(
      x, lin_W, lin_b, hbuf, nullptr, nullptr, nullptr, nullptr,
      last_dst, last_src, ea, enc_W, enc_b);

  for (int l = 0; l < 2; ++l) {
    k_table<<<1, 128, 0, stream>>>(e1_W + l * 128, e1_b + l * 128,
                                   e2_W + l * 128 * 128, e2_b + l * 128,
                                   tabA, tabB, tsort);
    k_agg<<<(N_NODES * 64 + 255) / 256, 256, 0, stream>>>(
        hbuf, swv, awv, excl, boff, tabA, tabB, tsort, eps + l, zin, N_NODES, E_EDGES);
    hipMemsetAsync(colsum, 0, 512 * sizeof(float), stream);
    k_gemm<128, 256, 1, false><<<N_NODES / 32, 256, 0, stream>>>(
        zin, m1_W + l * 128 * 256, m1_b + l * 256, z2, nullptr, nullptr,
        colsum, colsumsq, nullptr, nullptr, nullptr, nullptr, nullptr);
    k_bnfin<<<1, 256, 0, stream>>>(colsum, colsumsq, bn_g + l * 256, bn_b + l * 256,
                                   scale, shift);
    if (l == 0) {
      k_gemm<256, 128, 2, true><<<N_NODES / 32, 256, 0, stream>>>(
          z2, m2_W + l * 256 * 128, m2_b + l * 128, hbuf, scale, shift,
          nullptr, nullptr, nullptr, nullptr, nullptr, nullptr, nullptr);
    } else {
      k_gemm<256, 128, 2, false><<<N_NODES / 32, 256, 0, stream>>>(
          z2, nullptr == nullptr ? m2_W + l * 256 * 128 : nullptr, m2_b + l * 128, hbuf, scale, shift,
          nullptr, nullptr, nullptr, nullptr, nullptr, nullptr, nullptr);
    }
  }
}